// Round 1
// baseline (131.896 us; speedup 1.0000x reference)
//
#include <hip/hip_runtime.h>
#include <math.h>

#define Ydim 384
#define Xdim 512
#define Ldim 32
#define NPIX (Ydim * Xdim)

// -------- Kernel 1: per-pixel 9 bilinear SSD costs, channel-parallel --------
// 32 lanes per pixel (lane = channel). Coalesced feat0/feat1 loads.
__global__ __launch_bounds__(256) void qf_cost_kernel(
    const float* __restrict__ feat0,
    const float* __restrict__ feat1,
    const float* __restrict__ flow,
    float* __restrict__ cost)   // (NPIX, 9)
{
    int tid  = blockIdx.x * blockDim.x + threadIdx.x;
    int pix  = tid >> 5;
    int lane = threadIdx.x & 31;
    if (pix >= NPIX) return;
    int y = pix >> 9;      // X = 512
    int x = pix & (Xdim - 1);

    float u  = flow[pix * 3 + 0];
    float v  = flow[pix * 3 + 1];
    float f0 = feat0[pix * 32 + lane];

    // Match reference op order exactly: px = (gx + u) + ox, per-sample floor.
    float pxc = (float)x + u;
    float pyc = (float)y + v;

    int   c0[3], c1[3];
    float wx[3];
#pragma unroll
    for (int j = 0; j < 3; ++j) {
        float px = pxc + (float)(j - 1);
        float fx = floorf(px);
        wx[j] = px - fx;
        int xi = (int)fx;
        xi = min(max(xi, 0), Xdim - 1);
        c0[j] = xi;
        c1[j] = min(xi + 1, Xdim - 1);   // clip(x0_clipped + 1)
    }

    float cacc[9];
#pragma unroll
    for (int i = 0; i < 3; ++i) {
        float py = pyc + (float)(i - 1);
        float fy = floorf(py);
        float wyv = py - fy;
        int yi = (int)fy;
        yi = min(max(yi, 0), Ydim - 1);
        int r0 = yi;
        int r1 = min(yi + 1, Ydim - 1);
        int rb0 = r0 * Xdim;
        int rb1 = r1 * Xdim;
#pragma unroll
        for (int j = 0; j < 3; ++j) {
            float f00 = feat1[(rb0 + c0[j]) * 32 + lane];
            float f01 = feat1[(rb0 + c1[j]) * 32 + lane];
            float f10 = feat1[(rb1 + c0[j]) * 32 + lane];
            float f11 = feat1[(rb1 + c1[j]) * 32 + lane];
            float wxv = wx[j];
            float s = f00 * (1.f - wxv) * (1.f - wyv)
                    + f01 * wxv * (1.f - wyv)
                    + f10 * (1.f - wxv) * wyv
                    + f11 * wxv * wyv;
            float d = f0 - s;
            cacc[i * 3 + j] = d * d;
        }
    }

    // Reduce the 9 partial costs over the 32 channel lanes.
#pragma unroll
    for (int s = 16; s > 0; s >>= 1) {
#pragma unroll
        for (int k = 0; k < 9; ++k)
            cacc[k] += __shfl_xor(cacc[k], s, 32);
    }
    if (lane == 0) {
#pragma unroll
        for (int k = 0; k < 9; ++k)
            cost[pix * 9 + k] = cacc[k];
    }
}

// -------- Kernel 2: softmax + weighted 6x6 normal equations + solve --------
// One thread per pixel; fp64 internally (AtWA can have kappa ~ 6e4 when the
// softmax is near-one-hot; fp64 makes the solve error negligible).
__global__ __launch_bounds__(256) void qf_solve_kernel(
    const float* __restrict__ cost,
    float* __restrict__ out)    // (NPIX, 6)
{
    int pix = blockIdx.x * blockDim.x + threadIdx.x;
    if (pix >= NPIX) return;

    float c[9];
#pragma unroll
    for (int k = 0; k < 9; ++k) c[k] = cost[pix * 9 + k];

    float cmin = c[0];
#pragma unroll
    for (int k = 1; k < 9; ++k) cmin = fminf(cmin, c[k]);

    double e[9], sum = 0.0;
#pragma unroll
    for (int k = 0; k < 9; ++k) {
        e[k] = exp((double)(cmin - c[k]));
        sum += e[k];
    }
    double inv = 1.0 / sum;

    double M[6][6];
    double rhs[6];
#pragma unroll
    for (int i = 0; i < 6; ++i) {
        rhs[i] = 0.0;
#pragma unroll
        for (int j = 0; j < 6; ++j) M[i][j] = 0.0;
    }

#pragma unroll
    for (int k = 0; k < 9; ++k) {
        double w  = e[k] * inv;
        double ox = (double)(k % 3 - 1);
        double oy = (double)(k / 3 - 1);
        double a[6] = {ox * ox, oy * oy, ox * oy, ox, oy, 1.0};
        double wc = w * (double)c[k];
#pragma unroll
        for (int i = 0; i < 6; ++i) {
            rhs[i] += wc * a[i];
            double wai = w * a[i];
#pragma unroll
            for (int j = 0; j < 6; ++j) M[i][j] += wai * a[j];
        }
    }
#pragma unroll
    for (int i = 0; i < 6; ++i) M[i][i] += 1e-4;

    // Gaussian elimination, no pivoting (SPD).
#pragma unroll
    for (int p = 0; p < 6; ++p) {
        double ip = 1.0 / M[p][p];
#pragma unroll
        for (int r = 0; r < 6; ++r) {
            if (r > p) {
                double f = M[r][p] * ip;
#pragma unroll
                for (int cc = 0; cc < 6; ++cc)
                    if (cc > p) M[r][cc] -= f * M[p][cc];
                rhs[r] -= f * rhs[p];
            }
        }
    }
    double sol[6];
#pragma unroll
    for (int p = 5; p >= 0; --p) {
        double s = rhs[p];
#pragma unroll
        for (int cc = 0; cc < 6; ++cc)
            if (cc > p) s -= M[p][cc] * sol[cc];
        sol[p] = s / M[p][p];
    }

#pragma unroll
    for (int i = 0; i < 6; ++i) out[pix * 6 + i] = (float)sol[i];
}

extern "C" void kernel_launch(void* const* d_in, const int* in_sizes, int n_in,
                              void* d_out, int out_size, void* d_ws, size_t ws_size,
                              hipStream_t stream) {
    const float* feat0 = (const float*)d_in[0];
    const float* feat1 = (const float*)d_in[1];
    const float* flow  = (const float*)d_in[2];
    float* out  = (float*)d_out;
    float* cost = (float*)d_ws;   // NPIX * 9 floats = 7.1 MB

    int threads1 = NPIX * 32;
    qf_cost_kernel<<<dim3(threads1 / 256), dim3(256), 0, stream>>>(feat0, feat1, flow, cost);
    qf_solve_kernel<<<dim3((NPIX + 255) / 256), dim3(256), 0, stream>>>(cost, out);
}

// Round 2
// 116.108 us; speedup vs baseline: 1.1360x; 1.1360x over previous
//
#include <hip/hip_runtime.h>
#include <math.h>

#define Ydim 384
#define Xdim 512
#define NPIX (Ydim * Xdim)
#define EPS 1e-4

// -------- Kernel 1: per-pixel 9 bilinear SSD costs --------
// 8 lanes per pixel; lane handles 4 channels via float4. Coalesced 128B per
// tap-corner per group; bilinear weights amortized over 4 channels; 3-step
// butterfly reduce over the 8-lane subgroup.
__global__ __launch_bounds__(256) void qf_cost_kernel(
    const float* __restrict__ feat0,
    const float* __restrict__ feat1,
    const float* __restrict__ flow,
    float* __restrict__ cost)   // (NPIX, 9)
{
    int tid = blockIdx.x * blockDim.x + threadIdx.x;
    int pix = tid >> 3;
    int sub = tid & 7;
    if (pix >= NPIX) return;
    int y = pix >> 9;          // X = 512
    int x = pix & (Xdim - 1);

    float u = flow[pix * 3 + 0];
    float v = flow[pix * 3 + 1];
    const float4 f0 = *(const float4*)(feat0 + (size_t)pix * 32 + sub * 4);

    // Match reference op order exactly: px = (gx + u) + ox, per-sample floor.
    float pxc = (float)x + u;
    float pyc = (float)y + v;

    int   coff0[3], coff1[3];
    float wx[3];
#pragma unroll
    for (int j = 0; j < 3; ++j) {
        float px = pxc + (float)(j - 1);
        float fx = floorf(px);
        wx[j] = px - fx;
        int xi = (int)fx;
        xi = min(max(xi, 0), Xdim - 1);
        coff0[j] = xi * 32 + sub * 4;
        coff1[j] = min(xi + 1, Xdim - 1) * 32 + sub * 4;  // clip(x0_clipped+1)
    }

    float cacc[9];
#pragma unroll
    for (int i = 0; i < 3; ++i) {
        float py = pyc + (float)(i - 1);
        float fy = floorf(py);
        float wyv = py - fy;
        int yi = (int)fy;
        yi = min(max(yi, 0), Ydim - 1);
        int rb0 = yi * (Xdim * 32);
        int rb1 = min(yi + 1, Ydim - 1) * (Xdim * 32);
        float omwy = 1.f - wyv;
#pragma unroll
        for (int j = 0; j < 3; ++j) {
            const float4 f00 = *(const float4*)(feat1 + rb0 + coff0[j]);
            const float4 f01 = *(const float4*)(feat1 + rb0 + coff1[j]);
            const float4 f10 = *(const float4*)(feat1 + rb1 + coff0[j]);
            const float4 f11 = *(const float4*)(feat1 + rb1 + coff1[j]);
            float wxv = wx[j], omwx = 1.f - wxv;
            float w00 = omwx * omwy, w01 = wxv * omwy;
            float w10 = omwx * wyv,  w11 = wxv * wyv;
            float dx = f0.x - (f00.x * w00 + f01.x * w01 + f10.x * w10 + f11.x * w11);
            float dy = f0.y - (f00.y * w00 + f01.y * w01 + f10.y * w10 + f11.y * w11);
            float dz = f0.z - (f00.z * w00 + f01.z * w01 + f10.z * w10 + f11.z * w11);
            float dw = f0.w - (f00.w * w00 + f01.w * w01 + f10.w * w10 + f11.w * w11);
            cacc[i * 3 + j] = dx * dx + dy * dy + dz * dz + dw * dw;
        }
    }

    // Reduce over the 8 lanes of the subgroup (masks 1,2,4 stay in-group).
#pragma unroll
    for (int m = 1; m <= 4; m <<= 1) {
#pragma unroll
        for (int k = 0; k < 9; ++k)
            cacc[k] += __shfl_xor(cacc[k], m);
    }
    if (sub == 0) {
#pragma unroll
        for (int k = 0; k < 9; ++k)
            cost[(size_t)pix * 9 + k] = cacc[k];
    }
}

// -------- Kernel 2: softmax + moment-based 6x6 normal equations + solve ----
// One thread per pixel. fp32 softmax (expf), fp64 moments + symmetric
// elimination. Design matrix has x,y in {-1,0,1} => x^3=x, x^4=x^2, so AtWA
// reduces to 9 moments S_pq (p,q<=2) computed with adds only.
__global__ __launch_bounds__(256) void qf_solve_kernel(
    const float* __restrict__ cost,
    float* __restrict__ out)    // (NPIX, 6)
{
    int pix = blockIdx.x * blockDim.x + threadIdx.x;
    if (pix >= NPIX) return;

    float c[9];
#pragma unroll
    for (int k = 0; k < 9; ++k) c[k] = cost[(size_t)pix * 9 + k];

    float cmin = c[0];
#pragma unroll
    for (int k = 1; k < 9; ++k) cmin = fminf(cmin, c[k]);

    float e[9], sumf = 0.f;
#pragma unroll
    for (int k = 0; k < 9; ++k) {
        e[k] = expf(cmin - c[k]);
        sumf += e[k];
    }
    double invs = 1.0 / (double)sumf;

    double w[9], q[9];
#pragma unroll
    for (int k = 0; k < 9; ++k) {
        w[k] = (double)e[k] * invs;
        q[k] = w[k] * (double)c[k];
    }

    // Moments. k = i*3+j, ox = j-1, oy = i-1.
    double sc0 = w[0] + w[3] + w[6], sc2 = w[2] + w[5] + w[8];
    double sr0 = w[0] + w[1] + w[2], sr2 = w[6] + w[7] + w[8];
    double S10 = sc2 - sc0, S20 = sc2 + sc0;
    double S01 = sr2 - sr0, S02 = sr2 + sr0;
    double S11 = (w[0] + w[8]) - (w[2] + w[6]);
    double S21 = (w[6] + w[8]) - (w[0] + w[2]);
    double S12 = (w[2] + w[8]) - (w[0] + w[6]);
    double S22 = w[0] + w[2] + w[6] + w[8];
    double S00 = sr0 + w[3] + w[4] + w[5] + sr2;

    double qc0 = q[0] + q[3] + q[6], qc2 = q[2] + q[5] + q[8];
    double qr0 = q[0] + q[1] + q[2], qr2 = q[6] + q[7] + q[8];
    double T10 = qc2 - qc0, T20 = qc2 + qc0;
    double T01 = qr2 - qr0, T02 = qr2 + qr0;
    double T11 = (q[0] + q[8]) - (q[2] + q[6]);
    double T00 = qr0 + q[3] + q[4] + q[5] + qr2;

    double M[6][6], rhs[6], ip[6];
    M[0][0] = S20 + EPS; M[0][1] = S22; M[0][2] = S11; M[0][3] = S10; M[0][4] = S21; M[0][5] = S20;
    M[1][1] = S02 + EPS; M[1][2] = S11; M[1][3] = S12; M[1][4] = S01; M[1][5] = S02;
    M[2][2] = S22 + EPS; M[2][3] = S21; M[2][4] = S12; M[2][5] = S11;
    M[3][3] = S20 + EPS; M[3][4] = S11; M[3][5] = S10;
    M[4][4] = S02 + EPS; M[4][5] = S01;
    M[5][5] = S00 + EPS;
    rhs[0] = T20; rhs[1] = T02; rhs[2] = T11; rhs[3] = T10; rhs[4] = T01; rhs[5] = T00;

    // Symmetric elimination (SPD, no pivoting), upper triangle only.
#pragma unroll
    for (int p = 0; p < 6; ++p) {
        ip[p] = 1.0 / M[p][p];
#pragma unroll
        for (int r = p + 1; r < 6; ++r) {
            double f = M[p][r] * ip[p];   // M[r][p] == M[p][r] (symmetry kept)
#pragma unroll
            for (int cc = r; cc < 6; ++cc)
                M[r][cc] -= f * M[p][cc];
            rhs[r] -= f * rhs[p];
        }
    }
    double sol[6];
#pragma unroll
    for (int p = 5; p >= 0; --p) {
        double s2 = rhs[p];
#pragma unroll
        for (int cc = p + 1; cc < 6; ++cc) s2 -= M[p][cc] * sol[cc];
        sol[p] = s2 * ip[p];
    }

#pragma unroll
    for (int i = 0; i < 6; ++i) out[(size_t)pix * 6 + i] = (float)sol[i];
}

extern "C" void kernel_launch(void* const* d_in, const int* in_sizes, int n_in,
                              void* d_out, int out_size, void* d_ws, size_t ws_size,
                              hipStream_t stream) {
    const float* feat0 = (const float*)d_in[0];
    const float* feat1 = (const float*)d_in[1];
    const float* flow  = (const float*)d_in[2];
    float* out  = (float*)d_out;
    float* cost = (float*)d_ws;   // NPIX * 9 floats = 7.1 MB

    qf_cost_kernel<<<dim3(NPIX * 8 / 256), dim3(256), 0, stream>>>(feat0, feat1, flow, cost);
    qf_solve_kernel<<<dim3((NPIX + 255) / 256), dim3(256), 0, stream>>>(cost, out);
}

// Round 3
// 109.566 us; speedup vs baseline: 1.2038x; 1.0597x over previous
//
#include <hip/hip_runtime.h>
#include <math.h>

#define Ydim 384
#define Xdim 512
#define NPIX (Ydim * Xdim)
#define EPS 1e-4

__device__ __forceinline__ double fast_rcp64(double d) {
    // approx fp32 rcp + 2 fp64 Newton steps -> ~full fp64 accuracy, no IEEE div
    double r = (double)__builtin_amdgcn_rcpf((float)d);
    r = r * (2.0 - d * r);
    r = r * (2.0 - d * r);
    return r;
}

// Fused: per-pixel 9 bilinear SSD costs (8 lanes/pixel, float4 channels)
// -> LDS -> softmax + moment-form 6x6 normal equations + fp64 solve.
// Block 256 = 32 pixels; grid 6144.
__global__ __launch_bounds__(256) void qf_fused_kernel(
    const float* __restrict__ feat0,
    const float* __restrict__ feat1,
    const float* __restrict__ flow,
    float* __restrict__ out)    // (NPIX, 6)
{
    __shared__ float cost_lds[32 * 9];

    const int t   = threadIdx.x;
    const int g   = t >> 3;          // pixel group within block, 0..31
    const int sub = t & 7;           // 4 channels per lane
    const int pix = blockIdx.x * 32 + g;
    const int y = pix >> 9;          // X = 512
    const int x = pix & (Xdim - 1);

    const float u = flow[pix * 3 + 0];
    const float v = flow[pix * 3 + 1];
    const float4 f0 = *(const float4*)(feat0 + (size_t)pix * 32 + sub * 4);

    // Reference op order exactly: px = ((x+u)) + (j-1), per-tap floor/clip.
    const float pxc = (float)x + u;
    const float pyc = (float)y + v;

    int   c0[3], c1[3], r0[3], r1[3];
    float wx[3], wy[3];
#pragma unroll
    for (int j = 0; j < 3; ++j) {
        float px = pxc + (float)(j - 1);
        float fx = floorf(px);
        wx[j] = px - fx;
        int xi = min(max((int)fx, 0), Xdim - 1);
        c0[j] = xi;
        c1[j] = min(xi + 1, Xdim - 1);
        float py = pyc + (float)(j - 1);
        float fy = floorf(py);
        wy[j] = py - fy;
        int yi = min(max((int)fy, 0), Ydim - 1);
        r0[j] = yi;
        r1[j] = min(yi + 1, Ydim - 1);
    }

    float cacc[9];
    const bool fast = (c1[0] == c0[1]) & (c1[1] == c0[2])
                    & (r1[0] == r0[1]) & (r1[1] == r0[2]);

    if (fast) {
        // 4x4 unique corner grid: 16 loads instead of 36.
        const int cols[4] = {c0[0], c0[1], c0[2], c1[2]};
        const int rows[4] = {r0[0], r0[1], r0[2], r1[2]};
        float4 F[4][4];
#pragma unroll
        for (int r = 0; r < 4; ++r) {
            const float* rb = feat1 + ((size_t)rows[r] * Xdim) * 32 + sub * 4;
#pragma unroll
            for (int c = 0; c < 4; ++c)
                F[r][c] = *(const float4*)(rb + (size_t)cols[c] * 32);
        }
#pragma unroll
        for (int i = 0; i < 3; ++i) {
            float wyv = wy[i], omwy = 1.f - wyv;
#pragma unroll
            for (int j = 0; j < 3; ++j) {
                float wxv = wx[j], omwx = 1.f - wxv;
                float w00 = omwx * omwy, w01 = wxv * omwy;
                float w10 = omwx * wyv,  w11 = wxv * wyv;
                float4 a = F[i][j], b = F[i][j + 1], c = F[i + 1][j], d = F[i + 1][j + 1];
                float dx = f0.x - (a.x * w00 + b.x * w01 + c.x * w10 + d.x * w11);
                float dy = f0.y - (a.y * w00 + b.y * w01 + c.y * w10 + d.y * w11);
                float dz = f0.z - (a.z * w00 + b.z * w01 + c.z * w10 + d.z * w11);
                float dw = f0.w - (a.w * w00 + b.w * w01 + c.w * w10 + d.w * w11);
                cacc[i * 3 + j] = dx * dx + dy * dy + dz * dz + dw * dw;
            }
        }
    } else {
        // Border / binade-edge pixels: exact per-tap 36-load path.
#pragma unroll
        for (int i = 0; i < 3; ++i) {
            float wyv = wy[i], omwy = 1.f - wyv;
            int rb0 = r0[i] * (Xdim * 32);
            int rb1 = r1[i] * (Xdim * 32);
#pragma unroll
            for (int j = 0; j < 3; ++j) {
                const float4 f00 = *(const float4*)(feat1 + rb0 + c0[j] * 32 + sub * 4);
                const float4 f01 = *(const float4*)(feat1 + rb0 + c1[j] * 32 + sub * 4);
                const float4 f10 = *(const float4*)(feat1 + rb1 + c0[j] * 32 + sub * 4);
                const float4 f11 = *(const float4*)(feat1 + rb1 + c1[j] * 32 + sub * 4);
                float wxv = wx[j], omwx = 1.f - wxv;
                float w00 = omwx * omwy, w01 = wxv * omwy;
                float w10 = omwx * wyv,  w11 = wxv * wyv;
                float dx = f0.x - (f00.x * w00 + f01.x * w01 + f10.x * w10 + f11.x * w11);
                float dy = f0.y - (f00.y * w00 + f01.y * w01 + f10.y * w10 + f11.y * w11);
                float dz = f0.z - (f00.z * w00 + f01.z * w01 + f10.z * w10 + f11.z * w11);
                float dw = f0.w - (f00.w * w00 + f01.w * w01 + f10.w * w10 + f11.w * w11);
                cacc[i * 3 + j] = dx * dx + dy * dy + dz * dz + dw * dw;
            }
        }
    }

    // Reduce over the 8 lanes of the subgroup.
#pragma unroll
    for (int m = 1; m <= 4; m <<= 1) {
#pragma unroll
        for (int k = 0; k < 9; ++k)
            cacc[k] += __shfl_xor(cacc[k], m);
    }
    if (sub == 0) {
#pragma unroll
        for (int k = 0; k < 9; ++k)
            cost_lds[g * 9 + k] = cacc[k];
    }
    __syncthreads();

    if (t >= 32) return;

    // ---- Solve phase: lane t handles pixel blockBase + t ----
    float c[9];
#pragma unroll
    for (int k = 0; k < 9; ++k) c[k] = cost_lds[t * 9 + k];

    float cmin = c[0];
#pragma unroll
    for (int k = 1; k < 9; ++k) cmin = fminf(cmin, c[k]);

    float e[9], sumf = 0.f;
#pragma unroll
    for (int k = 0; k < 9; ++k) {
        e[k] = expf(cmin - c[k]);
        sumf += e[k];
    }
    float invs = 1.f / sumf;

    float w[9], q[9];
#pragma unroll
    for (int k = 0; k < 9; ++k) {
        w[k] = e[k] * invs;
        q[k] = w[k] * c[k];
    }

    // Moments (fp32, same precision class as reference's fp32 einsum).
    float sc0 = w[0] + w[3] + w[6], sc2 = w[2] + w[5] + w[8];
    float sr0 = w[0] + w[1] + w[2], sr2 = w[6] + w[7] + w[8];
    float S10 = sc2 - sc0, S20 = sc2 + sc0;
    float S01 = sr2 - sr0, S02 = sr2 + sr0;
    float S11 = (w[0] + w[8]) - (w[2] + w[6]);
    float S21 = (w[6] + w[8]) - (w[0] + w[2]);
    float S12 = (w[2] + w[8]) - (w[0] + w[6]);
    float S22 = w[0] + w[2] + w[6] + w[8];
    float S00 = sr0 + w[3] + w[4] + w[5] + sr2;

    float qc0 = q[0] + q[3] + q[6], qc2 = q[2] + q[5] + q[8];
    float qr0 = q[0] + q[1] + q[2], qr2 = q[6] + q[7] + q[8];
    float T10 = qc2 - qc0, T20 = qc2 + qc0;
    float T01 = qr2 - qr0, T02 = qr2 + qr0;
    float T11 = (q[0] + q[8]) - (q[2] + q[6]);
    float T00 = qr0 + q[3] + q[4] + q[5] + qr2;

    // fp64 symmetric elimination (SPD + eps), upper triangle only.
    double M[6][6], rhs[6], ip[6];
    M[0][0] = (double)S20 + EPS; M[0][1] = S22; M[0][2] = S11; M[0][3] = S10; M[0][4] = S21; M[0][5] = S20;
    M[1][1] = (double)S02 + EPS; M[1][2] = S11; M[1][3] = S12; M[1][4] = S01; M[1][5] = S02;
    M[2][2] = (double)S22 + EPS; M[2][3] = S21; M[2][4] = S12; M[2][5] = S11;
    M[3][3] = (double)S20 + EPS; M[3][4] = S11; M[3][5] = S10;
    M[4][4] = (double)S02 + EPS; M[4][5] = S01;
    M[5][5] = (double)S00 + EPS;
    rhs[0] = T20; rhs[1] = T02; rhs[2] = T11; rhs[3] = T10; rhs[4] = T01; rhs[5] = T00;

#pragma unroll
    for (int p = 0; p < 6; ++p) {
        ip[p] = fast_rcp64(M[p][p]);
#pragma unroll
        for (int r = p + 1; r < 6; ++r) {
            double f = M[p][r] * ip[p];
#pragma unroll
            for (int cc = r; cc < 6; ++cc)
                M[r][cc] -= f * M[p][cc];
            rhs[r] -= f * rhs[p];
        }
    }
    double sol[6];
#pragma unroll
    for (int p = 5; p >= 0; --p) {
        double s2 = rhs[p];
#pragma unroll
        for (int cc = p + 1; cc < 6; ++cc) s2 -= M[p][cc] * sol[cc];
        sol[p] = s2 * ip[p];
    }

    const int opix = blockIdx.x * 32 + t;
#pragma unroll
    for (int i = 0; i < 6; ++i) out[(size_t)opix * 6 + i] = (float)sol[i];
}

extern "C" void kernel_launch(void* const* d_in, const int* in_sizes, int n_in,
                              void* d_out, int out_size, void* d_ws, size_t ws_size,
                              hipStream_t stream) {
    const float* feat0 = (const float*)d_in[0];
    const float* feat1 = (const float*)d_in[1];
    const float* flow  = (const float*)d_in[2];
    float* out = (float*)d_out;

    qf_fused_kernel<<<dim3(NPIX / 32), dim3(256), 0, stream>>>(feat0, feat1, flow, out);
}